// Round 3
// baseline (221.806 us; speedup 1.0000x reference)
//
#include <hip/hip_runtime.h>

typedef __bf16 bf16;
typedef __bf16 bf16x4 __attribute__((ext_vector_type(4)));
typedef __bf16 bf16x8 __attribute__((ext_vector_type(8)));
typedef float f32x4 __attribute__((ext_vector_type(4)));

#define DEV __device__ __forceinline__

typedef const __attribute__((address_space(1))) void gvoid_t;
typedef __attribute__((address_space(3))) void lvoid_t;

DEV void gload_lds16(const void* g, void* l) {
  __builtin_amdgcn_global_load_lds((gvoid_t*)g, (lvoid_t*)l, 16, 0, 0);
}

DEV f32x4 mfma16(bf16x8 a, bf16x8 b, f32x4 c) {
  return __builtin_amdgcn_mfma_f32_16x16x32_bf16(a, b, c, 0, 0, 0);
}

// ---------------------------------------------------------------------------
// Kernel A: f32 -> bf16 conversion, 4 elements/thread
// ---------------------------------------------------------------------------
__global__ __launch_bounds__(256) void cvt4_kernel(const float* __restrict__ src,
                                                   bf16* __restrict__ dst, int n4) {
  int i = blockIdx.x * 256 + threadIdx.x;
  if (i >= n4) return;
  float4 f = reinterpret_cast<const float4*>(src)[i];
  bf16x4 o;
  o[0] = (bf16)f.x; o[1] = (bf16)f.y; o[2] = (bf16)f.z; o[3] = (bf16)f.w;
  reinterpret_cast<bf16x4*>(dst)[i] = o;
}

// ---------------------------------------------------------------------------
// Kernel B: fused QKV projection GEMM. 128x128 tile, BK=64, 4 waves.
// XCD-aware block swizzle (768 blocks = 8 XCD x 96).
// ---------------------------------------------------------------------------
__global__ __launch_bounds__(256) void gemm_qkv(
    const bf16* __restrict__ X, const bf16* __restrict__ W,
    const float* __restrict__ bq, const float* __restrict__ bk,
    const float* __restrict__ bv,
    bf16* __restrict__ Q, bf16* __restrict__ Kb, bf16* __restrict__ Vt) {
  __shared__ bf16 As[128 * 64];
  __shared__ bf16 Bs[128 * 64];
  const int t = threadIdx.x;
  const int lane = t & 63, w = t >> 6;
  const int wr = w >> 1, wc = w & 1;
  const int bid = blockIdx.x;
  const int swz = (bid & 7) * 96 + (bid >> 3);  // XCD swizzle, 768%8==0
  const int m0 = (swz / 24) * 128;
  const int n0 = (swz % 24) * 128;
  const int cl = lane & 15, g8 = (lane >> 4) * 8;

  f32x4 acc[4][4];
  for (int mi = 0; mi < 4; ++mi)
    for (int ni = 0; ni < 4; ++ni)
      for (int r = 0; r < 4; ++r) acc[mi][ni][r] = 0.0f;

  for (int k0 = 0; k0 < 1024; k0 += 64) {
#pragma unroll
    for (int i = 0; i < 4; ++i) {
      int c = i * 256 + t;
      int row = c >> 3, col8 = (c & 7) * 8;
      gload_lds16(X + (size_t)(m0 + row) * 1024 + k0 + col8, As + c * 8);
      gload_lds16(W + (size_t)(n0 + row) * 1024 + k0 + col8, Bs + c * 8);
    }
    __syncthreads();
#pragma unroll
    for (int kk = 0; kk < 64; kk += 32) {
      bf16x8 a[4], b[4];
#pragma unroll
      for (int mi = 0; mi < 4; ++mi)
        a[mi] = *(const bf16x8*)&As[(wr * 64 + mi * 16 + cl) * 64 + kk + g8];
#pragma unroll
      for (int ni = 0; ni < 4; ++ni)
        b[ni] = *(const bf16x8*)&Bs[(wc * 64 + ni * 16 + cl) * 64 + kk + g8];
      __builtin_amdgcn_s_setprio(1);
#pragma unroll
      for (int mi = 0; mi < 4; ++mi)
#pragma unroll
        for (int ni = 0; ni < 4; ++ni)
          acc[mi][ni] = mfma16(a[mi], b[ni], acc[mi][ni]);
      __builtin_amdgcn_s_setprio(0);
    }
    __syncthreads();
  }

  const int rq = (lane >> 4) * 4;
#pragma unroll
  for (int mi = 0; mi < 4; ++mi) {
#pragma unroll
    for (int ni = 0; ni < 4; ++ni) {
      const int n = n0 + wc * 64 + ni * 16 + cl;
#pragma unroll
      for (int r = 0; r < 4; ++r) {
        const int m = m0 + wr * 64 + mi * 16 + rq + r;
        const int b = m >> 11, s = m & 2047;
        float v = acc[mi][ni][r];
        if (n < 1024) {
          v += bq[n];
          const int h = n >> 6, hd = n & 63;
          Q[(((size_t)(b * 16 + h)) * 2048 + s) * 64 + hd] = (bf16)v;
        } else if (n < 2048) {
          const int n2 = n - 1024;
          v += bk[n2];
          const int h = n2 >> 6, hd = n2 & 63;
          Kb[(((size_t)(b * 16 + h)) * 2048 + s) * 64 + hd] = (bf16)v;
        } else {
          const int n2 = n - 2048;
          v += bv[n2];
          const int h = n2 >> 6, hd = n2 & 63;
          Vt[(((size_t)(b * 16 + h)) * 64 + hd) * 2048 + s] = (bf16)v;
        }
      }
    }
  }
}

// ---------------------------------------------------------------------------
// Kernel C: causal flash attention, v3 (pair-balanced).
// Block = 4 waves. Block p (0..15) of head bh owns q-tiles qhi=31-p and
// qlo=p (QBLK=64, wave owns 16 rows of each). One KV sweep (KVBLK=64,
// double-buffered LDS, XOR-swizzled) serves BOTH q-sets: kf/vf fragments
// are loaded once and feed both accumulator sets. Every block does exactly
// 33 q-tile-computations -> zero tail imbalance.
// Softmax: wave-scalar running max + defer-max (THR=8); row-sum via a 5th
// MFMA output column (ones B-fragment). P via per-wave swizzled LDS.
// ---------------------------------------------------------------------------
__global__ __launch_bounds__(256) void flash_attn(
    const bf16* __restrict__ Q, const bf16* __restrict__ K,
    const bf16* __restrict__ Vt, const int* __restrict__ amask,
    float* __restrict__ out) {
  __shared__ bf16 Ks[2][64 * 64];
  __shared__ bf16 Vs[2][64 * 64];
  __shared__ bf16 Ps[4][2][16 * 64];
  const int t = threadIdx.x, lane = t & 63, w = t >> 6;
  const int bh = blockIdx.x & 31;   // low bits -> same bh stays on one XCD
  const int p = blockIdx.x >> 5;    // 0..15
  const int qhi = 31 - p, qlo = p;
  const int b = bh >> 4, h = bh & 15;
  const int cl = lane & 15, g8 = (lane >> 4) * 8, rq = (lane >> 4) * 4;
  const int rowhi0 = qhi * 64 + w * 16;
  const int rowlo0 = qlo * 64 + w * 16;

  const bf16* Qp = Q + (size_t)bh * 2048 * 64;
  const bf16* Kp = K + (size_t)bh * 2048 * 64;
  const bf16* Vp = Vt + (size_t)bh * 64 * 2048;

  bf16x8 qhif[2], qlof[2];
#pragma unroll
  for (int ks = 0; ks < 2; ++ks) {
    qhif[ks] = *(const bf16x8*)&Qp[(size_t)(rowhi0 + cl) * 64 + ks * 32 + g8];
    qlof[ks] = *(const bf16x8*)&Qp[(size_t)(rowlo0 + cl) * 64 + ks * 32 + g8];
  }

  // ones B-fragment: B[0][k]=1 -> col 0 of D = rowsum
  bf16x8 ones;
#pragma unroll
  for (int j = 0; j < 8; ++j) ones[j] = (cl == 0) ? (bf16)1.0f : (bf16)0.0f;

  f32x4 ohi[5], olo[5];
#pragma unroll
  for (int nc = 0; nc < 5; ++nc)
#pragma unroll
    for (int r = 0; r < 4; ++r) { ohi[nc][r] = 0.0f; olo[nc][r] = 0.0f; }
  float mhi = -1e30f, mlo = -1e30f;

  const int ntiles = qhi + 1;

  // prologue: stage tile 0 into buf 0
#pragma unroll
  for (int pp = 0; pp < 2; ++pp) {
    int c = pp * 256 + t, row = c >> 3, sl = (c & 7) ^ (row & 7);
    gload_lds16(Kp + (size_t)row * 64 + sl * 8, &Ks[0][c * 8]);
    gload_lds16(Vp + (size_t)row * 2048 + sl * 8, &Vs[0][c * 8]);
  }
  __syncthreads();

  int buf = 0;
  for (int kt = 0; kt < ntiles; ++kt) {
    const int kv0 = kt * 64;
    // prefetch next tile (issued early; overlaps with all compute below)
    if (kt + 1 < ntiles) {
      const int nv0 = kv0 + 64;
#pragma unroll
      for (int pp = 0; pp < 2; ++pp) {
        int c = pp * 256 + t, row = c >> 3, sl = (c & 7) ^ (row & 7);
        gload_lds16(Kp + (size_t)(nv0 + row) * 64 + sl * 8, &Ks[buf ^ 1][c * 8]);
        gload_lds16(Vp + (size_t)row * 2048 + nv0 + sl * 8, &Vs[buf ^ 1][c * 8]);
      }
    }
    const bool lo = (kt <= qlo);  // block-uniform
    const int av = amask[b * 2048 + kv0 + lane];
    const unsigned long long padb = __ballot(av != 0);

    // ---- K fragments (shared by both q-sets)
    bf16x8 kf[2][4];
#pragma unroll
    for (int ks = 0; ks < 2; ++ks)
#pragma unroll
      for (int nj = 0; nj < 4; ++nj) {
        const int row = nj * 16 + cl;
        kf[ks][nj] = *(const bf16x8*)&Ks[buf][row * 64 +
                          ((ks * 32 + g8) ^ ((row & 7) << 3))];
      }

    // ---- QK^T
    f32x4 shi[4], slo[4];
#pragma unroll
    for (int nj = 0; nj < 4; ++nj)
#pragma unroll
      for (int r = 0; r < 4; ++r) { shi[nj][r] = 0.0f; slo[nj][r] = 0.0f; }
    __builtin_amdgcn_s_setprio(1);
#pragma unroll
    for (int ks = 0; ks < 2; ++ks)
#pragma unroll
      for (int nj = 0; nj < 4; ++nj)
        shi[nj] = mfma16(qhif[ks], kf[ks][nj], shi[nj]);
    if (lo) {
#pragma unroll
      for (int ks = 0; ks < 2; ++ks)
#pragma unroll
        for (int nj = 0; nj < 4; ++nj)
          slo[nj] = mfma16(qlof[ks], kf[ks][nj], slo[nj]);
    }
    __builtin_amdgcn_s_setprio(0);

    // ---- softmax (per set)
    {
      const bool needm = (kt == qhi) || (padb != 0ull);
      float sv[4][4], tm = -1e30f;
#pragma unroll
      for (int nj = 0; nj < 4; ++nj)
#pragma unroll
        for (int r = 0; r < 4; ++r) {
          float x = shi[nj][r] * 0.125f;
          if (needm) {
            const int col = kv0 + nj * 16 + cl;
            const int row = rowhi0 + rq + r;
            const bool bad = (col > row) || ((padb >> (nj * 16 + cl)) & 1ull);
            x = bad ? -1e30f : x;
          }
          sv[nj][r] = x;
          tm = fmaxf(tm, x);
        }
#pragma unroll
      for (int d = 1; d < 64; d <<= 1) tm = fmaxf(tm, __shfl_xor(tm, d, 64));
      if (tm > mhi + 8.0f) {  // defer-max: rescale only on real growth
        const float fr = __expf(mhi - tm);
        mhi = tm;
#pragma unroll
        for (int nc = 0; nc < 5; ++nc)
#pragma unroll
          for (int r = 0; r < 4; ++r) ohi[nc][r] *= fr;
      }
#pragma unroll
      for (int nj = 0; nj < 4; ++nj)
#pragma unroll
        for (int r = 0; r < 4; ++r) {
          const float pv = __expf(sv[nj][r] - mhi);
          const int row = rq + r;
          Ps[w][0][row * 64 + ((nj * 16 + cl) ^ ((row & 7) << 3))] = (bf16)pv;
        }
    }
    if (lo) {
      const bool needm = (kt == qlo) || (padb != 0ull);
      float sv[4][4], tm = -1e30f;
#pragma unroll
      for (int nj = 0; nj < 4; ++nj)
#pragma unroll
        for (int r = 0; r < 4; ++r) {
          float x = slo[nj][r] * 0.125f;
          if (needm) {
            const int col = kv0 + nj * 16 + cl;
            const int row = rowlo0 + rq + r;
            const bool bad = (col > row) || ((padb >> (nj * 16 + cl)) & 1ull);
            x = bad ? -1e30f : x;
          }
          sv[nj][r] = x;
          tm = fmaxf(tm, x);
        }
#pragma unroll
      for (int d = 1; d < 64; d <<= 1) tm = fmaxf(tm, __shfl_xor(tm, d, 64));
      if (tm > mlo + 8.0f) {
        const float fr = __expf(mlo - tm);
        mlo = tm;
#pragma unroll
        for (int nc = 0; nc < 5; ++nc)
#pragma unroll
          for (int r = 0; r < 4; ++r) olo[nc][r] *= fr;
      }
#pragma unroll
      for (int nj = 0; nj < 4; ++nj)
#pragma unroll
        for (int r = 0; r < 4; ++r) {
          const float pv = __expf(sv[nj][r] - mlo);
          const int row = rq + r;
          Ps[w][1][row * 64 + ((nj * 16 + cl) ^ ((row & 7) << 3))] = (bf16)pv;
        }
    }

    // ---- PV (vf shared by both q-sets)
    bf16x8 pahi[2], palo[2];
#pragma unroll
    for (int ks = 0; ks < 2; ++ks)
      pahi[ks] = *(const bf16x8*)&Ps[w][0][cl * 64 +
                      ((ks * 32 + g8) ^ ((cl & 7) << 3))];
    if (lo) {
#pragma unroll
      for (int ks = 0; ks < 2; ++ks)
        palo[ks] = *(const bf16x8*)&Ps[w][1][cl * 64 +
                        ((ks * 32 + g8) ^ ((cl & 7) << 3))];
    }
    __builtin_amdgcn_s_setprio(1);
#pragma unroll
    for (int ks = 0; ks < 2; ++ks) {
#pragma unroll
      for (int nc = 0; nc < 4; ++nc) {
        const int row = nc * 16 + cl;
        const bf16x8 vf = *(const bf16x8*)&Vs[buf][row * 64 +
                              ((ks * 32 + g8) ^ ((row & 7) << 3))];
        ohi[nc] = mfma16(pahi[ks], vf, ohi[nc]);
        if (lo) olo[nc] = mfma16(palo[ks], vf, olo[nc]);
      }
      ohi[4] = mfma16(pahi[ks], ones, ohi[4]);
      if (lo) olo[4] = mfma16(palo[ks], ones, olo[4]);
    }
    __builtin_amdgcn_s_setprio(0);
    __syncthreads();
    buf ^= 1;
  }

  // ---- epilogue: normalize by rowsum (col 0 of o[4], lanes cl==0)
#pragma unroll
  for (int r = 0; r < 4; ++r) {
    const float l = __shfl(ohi[4][r], lane & 48, 64);
    const float inv = 1.0f / l;
    const int row = rowhi0 + rq + r;
    float* op = &out[((size_t)b * 2048 + row) * 1024 + h * 64];
#pragma unroll
    for (int nc = 0; nc < 4; ++nc) op[nc * 16 + cl] = ohi[nc][r] * inv;
  }
#pragma unroll
  for (int r = 0; r < 4; ++r) {
    const float l = __shfl(olo[4][r], lane & 48, 64);
    const float inv = 1.0f / l;
    const int row = rowlo0 + rq + r;
    float* op = &out[((size_t)b * 2048 + row) * 1024 + h * 64];
#pragma unroll
    for (int nc = 0; nc < 4; ++nc) op[nc * 16 + cl] = olo[nc][r] * inv;
  }
}

// ---------------------------------------------------------------------------
extern "C" void kernel_launch(void* const* d_in, const int* in_sizes, int n_in,
                              void* d_out, int out_size, void* d_ws,
                              size_t ws_size, hipStream_t stream) {
  const float* hs = (const float*)d_in[0];
  const int* amask = (const int*)d_in[1];
  const float* Wq = (const float*)d_in[2];
  const float* bq = (const float*)d_in[3];
  const float* Wk = (const float*)d_in[4];
  const float* bk = (const float*)d_in[5];
  const float* Wv = (const float*)d_in[6];
  const float* bv = (const float*)d_in[7];
  float* out = (float*)d_out;

  char* ws = (char*)d_ws;
  bf16* Xb = (bf16*)ws;                               // 8 MB: [4096][1024]
  bf16* Wb = (bf16*)(ws + 8ull * 1024 * 1024);        // 6 MB: [3072][1024]
  bf16* Qb = (bf16*)(ws + 14ull * 1024 * 1024);       // 8 MB: [32][2048][64]
  bf16* Kb = (bf16*)(ws + 22ull * 1024 * 1024);       // 8 MB: [32][2048][64]
  bf16* Vtb = (bf16*)(ws + 30ull * 1024 * 1024);      // 8 MB: [32][64][2048]

  cvt4_kernel<<<4096, 256, 0, stream>>>(hs, Xb, 1048576);
  cvt4_kernel<<<1024, 256, 0, stream>>>(Wq, Wb, 262144);
  cvt4_kernel<<<1024, 256, 0, stream>>>(Wk, Wb + 1024 * 1024, 262144);
  cvt4_kernel<<<1024, 256, 0, stream>>>(Wv, Wb + 2 * 1024 * 1024, 262144);

  gemm_qkv<<<768, 256, 0, stream>>>(Xb, Wb, bq, bk, bv, Qb, Kb, Vtb);

  flash_attn<<<512, 256, 0, stream>>>(Qb, Kb, Vtb, amask, out);
}

// Round 4
// 102.805 us; speedup vs baseline: 2.1575x; 2.1575x over previous
//
#include <hip/hip_runtime.h>

typedef __bf16 bf16;
typedef __bf16 bf16x4 __attribute__((ext_vector_type(4)));
typedef __bf16 bf16x8 __attribute__((ext_vector_type(8)));
typedef float f32x4 __attribute__((ext_vector_type(4)));

#define DEV __device__ __forceinline__

typedef const __attribute__((address_space(1))) void gvoid_t;
typedef __attribute__((address_space(3))) void lvoid_t;

DEV void gload_lds16(const void* g, void* l) {
  __builtin_amdgcn_global_load_lds((gvoid_t*)g, (lvoid_t*)l, 16, 0, 0);
}

DEV f32x4 mfma16(bf16x8 a, bf16x8 b, f32x4 c) {
  return __builtin_amdgcn_mfma_f32_16x16x32_bf16(a, b, c, 0, 0, 0);
}

// ---------------------------------------------------------------------------
// Kernel A: fused f32 -> bf16 conversion of hidden_states + Wq|Wk|Wv
// (one launch instead of four). float4 per thread.
// ---------------------------------------------------------------------------
__global__ __launch_bounds__(256) void cvt_all(
    const float* __restrict__ hs, const float* __restrict__ Wq,
    const float* __restrict__ Wk, const float* __restrict__ Wv,
    bf16* __restrict__ Xb, bf16* __restrict__ Wb) {
  const int i = blockIdx.x * 256 + threadIdx.x;  // float4 index
  const float* src;
  bf16* dst;
  int off;
  if (i < 1048576) {                 // hidden_states: 4096*1024 f32
    src = hs; dst = Xb; off = i;
  } else {
    const int j = i - 1048576;       // weights: 3 x 1024*1024 f32
    const int sel = j >> 18;         // 262144 float4 each
    off = j & 262143;
    src = (sel == 0) ? Wq : (sel == 1) ? Wk : Wv;
    dst = Wb + (size_t)sel * 1048576;
  }
  float4 f = reinterpret_cast<const float4*>(src)[off];
  bf16x4 o;
  o[0] = (bf16)f.x; o[1] = (bf16)f.y; o[2] = (bf16)f.z; o[3] = (bf16)f.w;
  reinterpret_cast<bf16x4*>(dst)[off] = o;
}

// ---------------------------------------------------------------------------
// Kernel B: fused QKV projection GEMM. 128x128 tile, BK=64, 4 waves,
// XCD-aware swizzle. Vt epilogue stores packed as bf16x4 (s-consecutive).
// ---------------------------------------------------------------------------
__global__ __launch_bounds__(256) void gemm_qkv(
    const bf16* __restrict__ X, const bf16* __restrict__ W,
    const float* __restrict__ bq, const float* __restrict__ bk,
    const float* __restrict__ bv,
    bf16* __restrict__ Q, bf16* __restrict__ Kb, bf16* __restrict__ Vt) {
  __shared__ bf16 As[128 * 64];
  __shared__ bf16 Bs[128 * 64];
  const int t = threadIdx.x;
  const int lane = t & 63, w = t >> 6;
  const int wr = w >> 1, wc = w & 1;
  const int bid = blockIdx.x;
  const int swz = (bid & 7) * 96 + (bid >> 3);  // XCD swizzle, 768%8==0
  const int m0 = (swz / 24) * 128;
  const int n0 = (swz % 24) * 128;
  const int cl = lane & 15, g8 = (lane >> 4) * 8;

  f32x4 acc[4][4];
  for (int mi = 0; mi < 4; ++mi)
    for (int ni = 0; ni < 4; ++ni)
      for (int r = 0; r < 4; ++r) acc[mi][ni][r] = 0.0f;

  for (int k0 = 0; k0 < 1024; k0 += 64) {
#pragma unroll
    for (int i = 0; i < 4; ++i) {
      int c = i * 256 + t;
      int row = c >> 3, col8 = (c & 7) * 8;
      gload_lds16(X + (size_t)(m0 + row) * 1024 + k0 + col8, As + c * 8);
      gload_lds16(W + (size_t)(n0 + row) * 1024 + k0 + col8, Bs + c * 8);
    }
    __syncthreads();
#pragma unroll
    for (int kk = 0; kk < 64; kk += 32) {
      bf16x8 a[4], b[4];
#pragma unroll
      for (int mi = 0; mi < 4; ++mi)
        a[mi] = *(const bf16x8*)&As[(wr * 64 + mi * 16 + cl) * 64 + kk + g8];
#pragma unroll
      for (int ni = 0; ni < 4; ++ni)
        b[ni] = *(const bf16x8*)&Bs[(wc * 64 + ni * 16 + cl) * 64 + kk + g8];
      __builtin_amdgcn_s_setprio(1);
#pragma unroll
      for (int mi = 0; mi < 4; ++mi)
#pragma unroll
        for (int ni = 0; ni < 4; ++ni)
          acc[mi][ni] = mfma16(a[mi], b[ni], acc[mi][ni]);
      __builtin_amdgcn_s_setprio(0);
    }
    __syncthreads();
  }

  const int rq = (lane >> 4) * 4;
#pragma unroll
  for (int mi = 0; mi < 4; ++mi) {
#pragma unroll
    for (int ni = 0; ni < 4; ++ni) {
      const int n = n0 + wc * 64 + ni * 16 + cl;
      const int mbase = m0 + wr * 64 + mi * 16 + rq;
      const int b = mbase >> 11, s0 = mbase & 2047;
      if (n < 1024) {
        const float bias = bq[n];
        const int h = n >> 6, hd = n & 63;
#pragma unroll
        for (int r = 0; r < 4; ++r)
          Q[(((size_t)(b * 16 + h)) * 2048 + s0 + r) * 64 + hd] =
              (bf16)(acc[mi][ni][r] + bias);
      } else if (n < 2048) {
        const int n2 = n - 1024;
        const float bias = bk[n2];
        const int h = n2 >> 6, hd = n2 & 63;
#pragma unroll
        for (int r = 0; r < 4; ++r)
          Kb[(((size_t)(b * 16 + h)) * 2048 + s0 + r) * 64 + hd] =
              (bf16)(acc[mi][ni][r] + bias);
      } else {
        const int n2 = n - 2048;
        const float bias = bv[n2];
        const int h = n2 >> 6, hd = n2 & 63;
        bf16x4 pk;
#pragma unroll
        for (int r = 0; r < 4; ++r) pk[r] = (bf16)(acc[mi][ni][r] + bias);
        *(bf16x4*)&Vt[(((size_t)(b * 16 + h)) * 64 + hd) * 2048 + s0] = pk;
      }
    }
  }
}

// ---------------------------------------------------------------------------
// Kernel C: causal flash attention, v4 (wave-paired).
// Block = 8 waves (512 thr). Block p (0..15) of head bh: waves 0-3 own
// q-tile qhi=31-p (16 rows each), waves 4-7 own q-tile qlo=p. One KV sweep
// (KVBLK=64, double-buffered, XOR-swizzled LDS) serves both wave groups;
// every block does exactly 33 active wave-tile-units -> perfect balance,
// and each wave carries only ONE accumulator set (low VGPR).
// Softmax: wave-scalar running max + defer-max (THR=8); rowsum via a 5th
// MFMA output column (ones B-fragment). P via per-wave swizzled LDS.
// ---------------------------------------------------------------------------
__global__ __launch_bounds__(512, 4) void flash_attn(
    const bf16* __restrict__ Q, const bf16* __restrict__ K,
    const bf16* __restrict__ Vt, const int* __restrict__ amask,
    float* __restrict__ out) {
  __shared__ bf16 Ks[2][64 * 64];
  __shared__ bf16 Vs[2][64 * 64];
  __shared__ bf16 Ps[8][16 * 64];
  const int t = threadIdx.x, lane = t & 63, w = t >> 6;
  const int bh = blockIdx.x & 31;  // same bh -> same XCD (L2-resident KV)
  const int p = blockIdx.x >> 5;   // 0..15
  const int qt = (w < 4) ? (31 - p) : p;  // this wave's 64-row q tile
  const int b = bh >> 4, h = bh & 15;
  const int cl = lane & 15, g8 = (lane >> 4) * 8, rq = (lane >> 4) * 4;
  const int row0 = qt * 64 + (w & 3) * 16;
  const int ntiles = 32 - p;  // block stages qhi+1 tiles

  const bf16* Qp = Q + (size_t)bh * 2048 * 64;
  const bf16* Kp = K + (size_t)bh * 2048 * 64;
  const bf16* Vp = Vt + (size_t)bh * 64 * 2048;

  bf16x8 qf[2];
#pragma unroll
  for (int ks = 0; ks < 2; ++ks)
    qf[ks] = *(const bf16x8*)&Qp[(size_t)(row0 + cl) * 64 + ks * 32 + g8];

  // ones B-fragment: B[0][k]=1 -> col 0 of D = rowsum
  bf16x8 ones;
#pragma unroll
  for (int j = 0; j < 8; ++j) ones[j] = (cl == 0) ? (bf16)1.0f : (bf16)0.0f;

  f32x4 o[5];
#pragma unroll
  for (int nc = 0; nc < 5; ++nc)
#pragma unroll
    for (int r = 0; r < 4; ++r) o[nc][r] = 0.0f;
  float mrun = -1e30f;

  // prologue: stage tile 0 into buf 0 (512 threads, one 16B chunk each)
  {
    const int row = t >> 3, sl8 = ((t & 7) ^ (row & 7)) * 8;
    gload_lds16(Kp + (size_t)row * 64 + sl8, &Ks[0][t * 8]);
    gload_lds16(Vp + (size_t)row * 2048 + sl8, &Vs[0][t * 8]);
  }
  __syncthreads();

  int buf = 0;
  for (int kt = 0; kt < ntiles; ++kt) {
    const int kv0 = kt * 64;
    if (kt + 1 < ntiles) {  // prefetch next tile into buf^1
      const int row = t >> 3, sl8 = ((t & 7) ^ (row & 7)) * 8;
      gload_lds16(Kp + (size_t)(kv0 + 64 + row) * 64 + sl8, &Ks[buf ^ 1][t * 8]);
      gload_lds16(Vp + (size_t)row * 2048 + kv0 + 64 + sl8, &Vs[buf ^ 1][t * 8]);
    }
    if (kt <= qt) {  // wave-uniform
      const unsigned long long padb =
          __ballot(amask[b * 2048 + kv0 + lane] != 0);
      // ---- QK^T: S[16 x 64]
      f32x4 s4[4];
#pragma unroll
      for (int nj = 0; nj < 4; ++nj)
#pragma unroll
        for (int r = 0; r < 4; ++r) s4[nj][r] = 0.0f;
      __builtin_amdgcn_s_setprio(1);
#pragma unroll
      for (int ks = 0; ks < 2; ++ks) {
#pragma unroll
        for (int nj = 0; nj < 4; ++nj) {
          const int row = nj * 16 + cl;
          const bf16x8 kf = *(const bf16x8*)&Ks[buf][row * 64 +
                                ((ks * 32 + g8) ^ ((row & 7) << 3))];
          s4[nj] = mfma16(qf[ks], kf, s4[nj]);
        }
      }
      __builtin_amdgcn_s_setprio(0);
      // ---- scale + mask + wave max
      const bool needm = (kt == qt) || (padb != 0ull);
      float tm = -1e30f;
#pragma unroll
      for (int nj = 0; nj < 4; ++nj)
#pragma unroll
        for (int r = 0; r < 4; ++r) {
          float x = s4[nj][r] * 0.125f;
          if (needm) {
            const int col = kv0 + nj * 16 + cl;
            const int rowq = row0 + rq + r;
            const bool bad = (col > rowq) || ((padb >> (nj * 16 + cl)) & 1ull);
            x = bad ? -1e30f : x;
          }
          s4[nj][r] = x;
          tm = fmaxf(tm, x);
        }
#pragma unroll
      for (int d = 1; d < 64; d <<= 1) tm = fmaxf(tm, __shfl_xor(tm, d, 64));
      if (tm > mrun + 8.0f) {  // defer-max rescale (wave-uniform)
        const float fr = __expf(mrun - tm);
        mrun = tm;
#pragma unroll
        for (int nc = 0; nc < 5; ++nc)
#pragma unroll
          for (int r = 0; r < 4; ++r) o[nc][r] *= fr;
      }
      // ---- exp + P to swizzled LDS
#pragma unroll
      for (int nj = 0; nj < 4; ++nj)
#pragma unroll
        for (int r = 0; r < 4; ++r) {
          const float pv = __expf(s4[nj][r] - mrun);
          const int rr = rq + r;
          Ps[w][rr * 64 + ((nj * 16 + cl) ^ ((rr & 7) << 3))] = (bf16)pv;
        }
      // ---- PV: O[16 x 64] += P[16 x 64] @ V^T
      __builtin_amdgcn_s_setprio(1);
#pragma unroll
      for (int ks = 0; ks < 2; ++ks) {
        const bf16x8 pa = *(const bf16x8*)&Ps[w][cl * 64 +
                              ((ks * 32 + g8) ^ ((cl & 7) << 3))];
#pragma unroll
        for (int nc = 0; nc < 4; ++nc) {
          const int row = nc * 16 + cl;
          const bf16x8 vf = *(const bf16x8*)&Vs[buf][row * 64 +
                                ((ks * 32 + g8) ^ ((row & 7) << 3))];
          o[nc] = mfma16(pa, vf, o[nc]);
        }
        o[4] = mfma16(pa, ones, o[4]);
      }
      __builtin_amdgcn_s_setprio(0);
    }
    __syncthreads();
    buf ^= 1;
  }

  // ---- epilogue: normalize by rowsum (col 0 of o[4])
#pragma unroll
  for (int r = 0; r < 4; ++r) {
    const float l = __shfl(o[4][r], lane & 48, 64);
    const float inv = 1.0f / l;
    const int rowg = row0 + rq + r;
    float* op = &out[((size_t)b * 2048 + rowg) * 1024 + h * 64];
#pragma unroll
    for (int nc = 0; nc < 4; ++nc) op[nc * 16 + cl] = o[nc][r] * inv;
  }
}

// ---------------------------------------------------------------------------
extern "C" void kernel_launch(void* const* d_in, const int* in_sizes, int n_in,
                              void* d_out, int out_size, void* d_ws,
                              size_t ws_size, hipStream_t stream) {
  const float* hs = (const float*)d_in[0];
  const int* amask = (const int*)d_in[1];
  const float* Wq = (const float*)d_in[2];
  const float* bq = (const float*)d_in[3];
  const float* Wk = (const float*)d_in[4];
  const float* bk = (const float*)d_in[5];
  const float* Wv = (const float*)d_in[6];
  const float* bv = (const float*)d_in[7];
  float* out = (float*)d_out;

  char* ws = (char*)d_ws;
  bf16* Xb = (bf16*)ws;                               // 8 MB: [4096][1024]
  bf16* Wb = (bf16*)(ws + 8ull * 1024 * 1024);        // 6 MB: [3072][1024]
  bf16* Qb = (bf16*)(ws + 14ull * 1024 * 1024);       // 8 MB: [32][2048][64]
  bf16* Kb = (bf16*)(ws + 22ull * 1024 * 1024);       // 8 MB: [32][2048][64]
  bf16* Vtb = (bf16*)(ws + 30ull * 1024 * 1024);      // 8 MB: [32][64][2048]

  cvt_all<<<7168, 256, 0, stream>>>(hs, Wq, Wk, Wv, Xb, Wb);
  gemm_qkv<<<768, 256, 0, stream>>>(Xb, Wb, bq, bk, bv, Qb, Kb, Vtb);
  flash_attn<<<512, 512, 0, stream>>>(Qb, Kb, Vtb, amask, out);
}

// Round 5
// 100.573 us; speedup vs baseline: 2.2054x; 1.0222x over previous
//
#include <hip/hip_runtime.h>

typedef __bf16 bf16;
typedef __bf16 bf16x4 __attribute__((ext_vector_type(4)));
typedef __bf16 bf16x8 __attribute__((ext_vector_type(8)));
typedef float f32x4 __attribute__((ext_vector_type(4)));

#define DEV __device__ __forceinline__

typedef const __attribute__((address_space(1))) void gvoid_t;
typedef __attribute__((address_space(3))) void lvoid_t;

DEV void gload_lds16(const void* g, void* l) {
  __builtin_amdgcn_global_load_lds((gvoid_t*)g, (lvoid_t*)l, 16, 0, 0);
}

DEV f32x4 mfma16(bf16x8 a, bf16x8 b, f32x4 c) {
  return __builtin_amdgcn_mfma_f32_16x16x32_bf16(a, b, c, 0, 0, 0);
}

// scores use exp2: Q is pre-scaled by 0.125 * log2(e) in the GEMM epilogue.
#define QSCALE 0.18033688011112042f

// ---------------------------------------------------------------------------
// Kernel A: fused f32 -> bf16 conversion of hidden_states + Wq|Wk|Wv.
// ---------------------------------------------------------------------------
__global__ __launch_bounds__(256) void cvt_all(
    const float* __restrict__ hs, const float* __restrict__ Wq,
    const float* __restrict__ Wk, const float* __restrict__ Wv,
    bf16* __restrict__ Xb, bf16* __restrict__ Wb) {
  const int i = blockIdx.x * 256 + threadIdx.x;  // float4 index
  const float* src;
  bf16* dst;
  int off;
  if (i < 1048576) {
    src = hs; dst = Xb; off = i;
  } else {
    const int j = i - 1048576;
    const int sel = j >> 18;
    off = j & 262143;
    src = (sel == 0) ? Wq : (sel == 1) ? Wk : Wv;
    dst = Wb + (size_t)sel * 1048576;
  }
  float4 f = reinterpret_cast<const float4*>(src)[off];
  bf16x4 o;
  o[0] = (bf16)f.x; o[1] = (bf16)f.y; o[2] = (bf16)f.z; o[3] = (bf16)f.w;
  reinterpret_cast<bf16x4*>(dst)[off] = o;
}

// ---------------------------------------------------------------------------
// Kernel B: fused QKV projection GEMM. 128x128 tile, BK=64, 4 waves,
// XCD swizzle. Q epilogue pre-scales by 0.125*log2(e) (attention uses exp2).
// ---------------------------------------------------------------------------
__global__ __launch_bounds__(256) void gemm_qkv(
    const bf16* __restrict__ X, const bf16* __restrict__ W,
    const float* __restrict__ bq, const float* __restrict__ bk,
    const float* __restrict__ bv,
    bf16* __restrict__ Q, bf16* __restrict__ Kb, bf16* __restrict__ Vt) {
  __shared__ bf16 As[128 * 64];
  __shared__ bf16 Bs[128 * 64];
  const int t = threadIdx.x;
  const int lane = t & 63, w = t >> 6;
  const int wr = w >> 1, wc = w & 1;
  const int bid = blockIdx.x;
  const int swz = (bid & 7) * 96 + (bid >> 3);  // XCD swizzle, 768%8==0
  const int m0 = (swz / 24) * 128;
  const int n0 = (swz % 24) * 128;
  const int cl = lane & 15, g8 = (lane >> 4) * 8;

  f32x4 acc[4][4];
  for (int mi = 0; mi < 4; ++mi)
    for (int ni = 0; ni < 4; ++ni)
      for (int r = 0; r < 4; ++r) acc[mi][ni][r] = 0.0f;

  for (int k0 = 0; k0 < 1024; k0 += 64) {
#pragma unroll
    for (int i = 0; i < 4; ++i) {
      int c = i * 256 + t;
      int row = c >> 3, col8 = (c & 7) * 8;
      gload_lds16(X + (size_t)(m0 + row) * 1024 + k0 + col8, As + c * 8);
      gload_lds16(W + (size_t)(n0 + row) * 1024 + k0 + col8, Bs + c * 8);
    }
    __syncthreads();
#pragma unroll
    for (int kk = 0; kk < 64; kk += 32) {
      bf16x8 a[4], b[4];
#pragma unroll
      for (int mi = 0; mi < 4; ++mi)
        a[mi] = *(const bf16x8*)&As[(wr * 64 + mi * 16 + cl) * 64 + kk + g8];
#pragma unroll
      for (int ni = 0; ni < 4; ++ni)
        b[ni] = *(const bf16x8*)&Bs[(wc * 64 + ni * 16 + cl) * 64 + kk + g8];
      __builtin_amdgcn_s_setprio(1);
#pragma unroll
      for (int mi = 0; mi < 4; ++mi)
#pragma unroll
        for (int ni = 0; ni < 4; ++ni)
          acc[mi][ni] = mfma16(a[mi], b[ni], acc[mi][ni]);
      __builtin_amdgcn_s_setprio(0);
    }
    __syncthreads();
  }

  const int rq = (lane >> 4) * 4;
#pragma unroll
  for (int mi = 0; mi < 4; ++mi) {
#pragma unroll
    for (int ni = 0; ni < 4; ++ni) {
      const int n = n0 + wc * 64 + ni * 16 + cl;
      const int mbase = m0 + wr * 64 + mi * 16 + rq;
      const int b = mbase >> 11, s0 = mbase & 2047;
      if (n < 1024) {
        const float bias = bq[n];
        const int h = n >> 6, hd = n & 63;
#pragma unroll
        for (int r = 0; r < 4; ++r)
          Q[(((size_t)(b * 16 + h)) * 2048 + s0 + r) * 64 + hd] =
              (bf16)((acc[mi][ni][r] + bias) * QSCALE);
      } else if (n < 2048) {
        const int n2 = n - 1024;
        const float bias = bk[n2];
        const int h = n2 >> 6, hd = n2 & 63;
#pragma unroll
        for (int r = 0; r < 4; ++r)
          Kb[(((size_t)(b * 16 + h)) * 2048 + s0 + r) * 64 + hd] =
              (bf16)(acc[mi][ni][r] + bias);
      } else {
        const int n2 = n - 2048;
        const float bias = bv[n2];
        const int h = n2 >> 6, hd = n2 & 63;
        bf16x4 pk;
#pragma unroll
        for (int r = 0; r < 4; ++r) pk[r] = (bf16)(acc[mi][ni][r] + bias);
        *(bf16x4*)&Vt[(((size_t)(b * 16 + h)) * 64 + hd) * 2048 + s0] = pk;
      }
    }
  }
}

// ---------------------------------------------------------------------------
// Kernel C: causal flash attention, v5 (wave-paired + mask hoist + exp2).
// Block = 8 waves (512 thr); waves 0-3 own q-tile qhi=31-p, waves 4-7 own
// qlo=p. KVBLK=64 double-buffered XOR-swizzled LDS. Pad-mask ballots for
// all 32 KV tiles precomputed into LDS (no VMEM in the main loop except
// prefetch -> double-buffer overlap is real). Softmax in exp2 domain
// (scale pre-folded into Q); wave-scalar defer-max; rowsum via ones-column
// MFMA.
// ---------------------------------------------------------------------------
__global__ __launch_bounds__(512) void flash_attn(
    const bf16* __restrict__ Q, const bf16* __restrict__ K,
    const bf16* __restrict__ Vt, const int* __restrict__ amask,
    float* __restrict__ out) {
  __shared__ bf16 Ks[2][64 * 64];
  __shared__ bf16 Vs[2][64 * 64];
  __shared__ bf16 Ps[8][16 * 64];
  __shared__ unsigned long long mk[32];
  const int t = threadIdx.x, lane = t & 63, w = t >> 6;
  const int bh = blockIdx.x & 31;  // same bh -> same XCD (L2-resident KV)
  const int p = blockIdx.x >> 5;   // 0..15
  const int qt = (w < 4) ? (31 - p) : p;  // this wave's 64-row q tile
  const int b = bh >> 4, h = bh & 15;
  const int cl = lane & 15, g8 = (lane >> 4) * 8, rq = (lane >> 4) * 4;
  const int row0 = qt * 64 + (w & 3) * 16;
  const int ntiles = 32 - p;

  const bf16* Qp = Q + (size_t)bh * 2048 * 64;
  const bf16* Kp = K + (size_t)bh * 2048 * 64;
  const bf16* Vp = Vt + (size_t)bh * 64 * 2048;

  bf16x8 qf[2];
#pragma unroll
  for (int ks = 0; ks < 2; ++ks)
    qf[ks] = *(const bf16x8*)&Qp[(size_t)(row0 + cl) * 64 + ks * 32 + g8];

  // ones B-fragment: B[0][k]=1 -> col 0 of D = rowsum
  bf16x8 ones;
#pragma unroll
  for (int j = 0; j < 8; ++j) ones[j] = (cl == 0) ? (bf16)1.0f : (bf16)0.0f;

  f32x4 o[5];
#pragma unroll
  for (int nc = 0; nc < 5; ++nc)
#pragma unroll
    for (int r = 0; r < 4; ++r) o[nc][r] = 0.0f;
  float mrun = -1e30f;

  // prologue: precompute pad-mask ballots for all 32 KV tiles (hoists all
  // VMEM out of the main loop), and stage tile 0 into buf 0.
#pragma unroll
  for (int i = 0; i < 4; ++i) {
    const int kt = w * 4 + i;
    const unsigned long long bal =
        __ballot(amask[b * 2048 + kt * 64 + lane] != 0);
    if (lane == 0) mk[kt] = bal;
  }
  {
    const int row = t >> 3, sl8 = ((t & 7) ^ (row & 7)) * 8;
    gload_lds16(Kp + (size_t)row * 64 + sl8, &Ks[0][t * 8]);
    gload_lds16(Vp + (size_t)row * 2048 + sl8, &Vs[0][t * 8]);
  }
  __syncthreads();

  int buf = 0;
  for (int kt = 0; kt < ntiles; ++kt) {
    const int kv0 = kt * 64;
    if (kt + 1 < ntiles) {  // prefetch next tile into buf^1
      const int row = t >> 3, sl8 = ((t & 7) ^ (row & 7)) * 8;
      gload_lds16(Kp + (size_t)(kv0 + 64 + row) * 64 + sl8, &Ks[buf ^ 1][t * 8]);
      gload_lds16(Vp + (size_t)row * 2048 + kv0 + 64 + sl8, &Vs[buf ^ 1][t * 8]);
    }
    if (kt <= qt) {  // wave-uniform
      const unsigned long long padb = mk[kt];
      // ---- QK^T: S[16 x 64] (exp2 domain, scale pre-folded into Q)
      f32x4 s4[4];
#pragma unroll
      for (int nj = 0; nj < 4; ++nj)
#pragma unroll
        for (int r = 0; r < 4; ++r) s4[nj][r] = 0.0f;
      __builtin_amdgcn_s_setprio(1);
#pragma unroll
      for (int ks = 0; ks < 2; ++ks) {
#pragma unroll
        for (int nj = 0; nj < 4; ++nj) {
          const int row = nj * 16 + cl;
          const bf16x8 kf = *(const bf16x8*)&Ks[buf][row * 64 +
                                ((ks * 32 + g8) ^ ((row & 7) << 3))];
          s4[nj] = mfma16(qf[ks], kf, s4[nj]);
        }
      }
      __builtin_amdgcn_s_setprio(0);
      // ---- mask (diagonal / padded only) + wave max
      const bool needm = (kt == qt) || (padb != 0ull);
      float tm = -1e30f;
#pragma unroll
      for (int nj = 0; nj < 4; ++nj)
#pragma unroll
        for (int r = 0; r < 4; ++r) {
          float x = s4[nj][r];
          if (needm) {
            const int col = kv0 + nj * 16 + cl;
            const int rowq = row0 + rq + r;
            const bool bad = (col > rowq) || ((padb >> (nj * 16 + cl)) & 1ull);
            x = bad ? -1e30f : x;
          }
          s4[nj][r] = x;
          tm = fmaxf(tm, x);
        }
#pragma unroll
      for (int d = 1; d < 64; d <<= 1) tm = fmaxf(tm, __shfl_xor(tm, d, 64));
      if (tm > mrun + 8.0f) {  // defer-max (2^8 = 256 max P, bf16-safe)
        const float fr = exp2f(mrun - tm);
        mrun = tm;
#pragma unroll
        for (int nc = 0; nc < 5; ++nc)
#pragma unroll
          for (int r = 0; r < 4; ++r) o[nc][r] *= fr;
      }
      // ---- exp2 + P to swizzled LDS
#pragma unroll
      for (int nj = 0; nj < 4; ++nj)
#pragma unroll
        for (int r = 0; r < 4; ++r) {
          const float pv = exp2f(s4[nj][r] - mrun);
          const int rr = rq + r;
          Ps[w][rr * 64 + ((nj * 16 + cl) ^ ((rr & 7) << 3))] = (bf16)pv;
        }
      // ---- PV: O[16 x 64] += P[16 x 64] @ V^T
      __builtin_amdgcn_s_setprio(1);
#pragma unroll
      for (int ks = 0; ks < 2; ++ks) {
        const bf16x8 pa = *(const bf16x8*)&Ps[w][cl * 64 +
                              ((ks * 32 + g8) ^ ((cl & 7) << 3))];
#pragma unroll
        for (int nc = 0; nc < 4; ++nc) {
          const int row = nc * 16 + cl;
          const bf16x8 vf = *(const bf16x8*)&Vs[buf][row * 64 +
                                ((ks * 32 + g8) ^ ((row & 7) << 3))];
          o[nc] = mfma16(pa, vf, o[nc]);
        }
        o[4] = mfma16(pa, ones, o[4]);
      }
      __builtin_amdgcn_s_setprio(0);
    }
    __syncthreads();
    buf ^= 1;
  }

  // ---- epilogue: normalize by rowsum (col 0 of o[4])
#pragma unroll
  for (int r = 0; r < 4; ++r) {
    const float l = __shfl(o[4][r], lane & 48, 64);
    const float inv = 1.0f / l;
    const int rowg = row0 + rq + r;
    float* op = &out[((size_t)b * 2048 + rowg) * 1024 + h * 64];
#pragma unroll
    for (int nc = 0; nc < 4; ++nc) op[nc * 16 + cl] = o[nc][r] * inv;
  }
}

// ---------------------------------------------------------------------------
extern "C" void kernel_launch(void* const* d_in, const int* in_sizes, int n_in,
                              void* d_out, int out_size, void* d_ws,
                              size_t ws_size, hipStream_t stream) {
  const float* hs = (const float*)d_in[0];
  const int* amask = (const int*)d_in[1];
  const float* Wq = (const float*)d_in[2];
  const float* bq = (const float*)d_in[3];
  const float* Wk = (const float*)d_in[4];
  const float* bk = (const float*)d_in[5];
  const float* Wv = (const float*)d_in[6];
  const float* bv = (const float*)d_in[7];
  float* out = (float*)d_out;

  char* ws = (char*)d_ws;
  bf16* Xb = (bf16*)ws;                               // 8 MB: [4096][1024]
  bf16* Wb = (bf16*)(ws + 8ull * 1024 * 1024);        // 6 MB: [3072][1024]
  bf16* Qb = (bf16*)(ws + 14ull * 1024 * 1024);       // 8 MB: [32][2048][64]
  bf16* Kb = (bf16*)(ws + 22ull * 1024 * 1024);       // 8 MB: [32][2048][64]
  bf16* Vtb = (bf16*)(ws + 30ull * 1024 * 1024);      // 8 MB: [32][64][2048]

  cvt_all<<<7168, 256, 0, stream>>>(hs, Wq, Wk, Wv, Xb, Wb);
  gemm_qkv<<<768, 256, 0, stream>>>(Xb, Wb, bq, bk, bv, Qb, Kb, Vtb);
  flash_attn<<<512, 512, 0, stream>>>(Qb, Kb, Vtb, amask, out);
}